// Round 1
// baseline (603.381 us; speedup 1.0000x reference)
//
#include <hip/hip_runtime.h>
#include <math.h>

#define N_NODES 8192
#define N_COMM 16
#define DIMS 64
#define MROWS 4                      // ricci rows per block
#define JQ 2                         // j-pair per thread (was 4): halves p[] regs
#define JPI (256 * JQ)               // 512 j's per block-iteration
#define ITERS (N_NODES / JPI)        // 16 iterations, full j-range per block

typedef float v4f __attribute__((ext_vector_type(4)));
typedef float v2f __attribute__((ext_vector_type(2)));

// ---------------------------------------------------------------------------
// Kernel 1: pi[i,k] = softmax_k( sqrt(d_euc^2 + d_lor^2 + d_sph^2) )
// One lane per (node, k): t = i*16 + k. 16-lane softmax via shfl_xor(1,2,4,8).
// Row-major pi only (piT dropped: k_main now reads pi rows contiguously).
// Thread 0 zeroes the accumulators + finish counter (replaces host memset;
// kernel-boundary ordering makes this visible to k_main).
// ---------------------------------------------------------------------------
__global__ __launch_bounds__(256) void k_pi(
    const float* __restrict__ node,   // (3, 8192, 64)
    const float* __restrict__ comm,   // (16, 64)
    float* __restrict__ pi,           // (8192, 16)
    double* __restrict__ accum,       // [0]=intra, [1]=inter
    unsigned* __restrict__ ctr)       // k_main finish counter
{
  const int t = blockIdx.x * blockDim.x + threadIdx.x;  // 0..131071
  if (t == 0) { accum[0] = 0.0; accum[1] = 0.0; *ctr = 0u; }
  const int i = t >> 4;
  const int k = t & 15;

  const float* xe = node + (size_t)i * DIMS;                  // Euclidean (curv 0)
  const float* xl = xe + (size_t)N_NODES * DIMS;              // Lorentz  (curv -1)
  const float* xs = xl + (size_t)N_NODES * DIMS;              // Sphere   (curv +1)
  const float* c  = comm + k * DIMS;

  float de = 0.f, il = 0.f, isp = 0.f;
#pragma unroll
  for (int d = 0; d < DIMS; d += 4) {
    v4f a  = *(const v4f*)(xe + d);
    v4f b  = *(const v4f*)(xl + d);
    v4f e  = *(const v4f*)(xs + d);
    v4f cv = *(const v4f*)(c + d);
    v4f df = a - cv;
    de  += df.x * df.x + df.y * df.y + df.z * df.z + df.w * df.w;
    il  += b.x * cv.x + b.y * cv.y + b.z * cv.z + b.w * cv.w;
    isp += e.x * cv.x + e.y * cv.y + e.z * cv.z + e.w * cv.w;
  }

  // Lorentz (kk = 1): lip = <x,c> - 2*x0*c0 ; d = arccosh(max(-lip, 1+eps))
  float lip = il - 2.0f * xl[0] * c[0];
  float arg = fmaxf(-lip, 1.0f + 1e-7f);
  float d1  = acoshf(arg);
  // Sphere: d = arccos(clip(<x,c>, -1+eps, 1-eps))
  float cs = fminf(fmaxf(isp, -1.0f + 1e-7f), 1.0f - 1e-7f);
  float d2 = acosf(cs);

  float dn = sqrtf(de + d1 * d1 + d2 * d2);

  // softmax over the 16 lanes sharing this node (lane mask bits 0..3)
  float m = dn;
#pragma unroll
  for (int off = 1; off < 16; off <<= 1) m = fmaxf(m, __shfl_xor(m, off));
  float ex = expf(dn - m);
  float ss = ex;
#pragma unroll
  for (int off = 1; off < 16; off <<= 1) ss += __shfl_xor(ss, off);

  pi[t] = ex / ss;                   // coalesced
}

// ---------------------------------------------------------------------------
// Kernel 2: single streaming pass over ricci, j-PAIR per thread (JQ=2).
// Register diet vs previous round: acc stays 64, p[] halves to 32 (two pi
// rows = 128 contiguous bytes -> 8 dwordx4 off ONE base, immediate offsets
// 0..112 -- no more 16 strided piT addresses), rv ping-pong halves to 16.
// Core ~112 VGPR -> target <=128 -> 4 waves/SIMD (was ~190 -> 2 waves/SIMD):
// doubles the latency-hiding pool for the 1-iter-ahead HBM prefetch.
// ISSUE-ORDER DISCIPLINE KEPT (vmcnt retires in issue order):
//   [8 pi dwordx4 loads]   (L2-resident, oldest)
//   [4 ricci dwordx2 prefetch for NEXT iter]  (newest -> never waited here)
//   [128 FMAs consuming this iter's pi + rv prefetched LAST iteration]
// Everything consumed is >= 1 iteration old; rv gets a full iter to land.
// Per-block j-phase rotation decorrelates cross-block address streams.
// NO min-waves launch bound (R4 lesson: (256,4) clamped to 64 VGPR -> spill).
// Epilogue: last block to finish computes the final scalar (k_final fused).
// ---------------------------------------------------------------------------
__global__ __launch_bounds__(256) void k_main(
    const float* __restrict__ ricci,   // (8192, 8192)
    const float* __restrict__ pi,      // (8192, 16) row-major
    const float* __restrict__ alpha,   // scalar
    double* __restrict__ accum,        // [0]=intra_sum, [1]=inter_sum
    unsigned* __restrict__ ctr,
    float* __restrict__ out)
{
  const int i0  = blockIdx.x * MROWS;       // 2048 blocks
  const int tid = threadIdx.x;
  const int ph  = blockIdx.x & (ITERS - 1); // j-phase ring (16 phases)
  const float* __restrict__ rbase = ricci + (size_t)i0 * N_NODES;

  v4f acc[MROWS][4];                        // 64 VGPRs: [row][k-quad]
#pragma unroll
  for (int r = 0; r < MROWS; ++r)
#pragma unroll
    for (int q = 0; q < 4; ++q) acc[r][q] = (v4f)0.f;

  v2f rv[2][MROWS];                         // 16 VGPRs (ping-pong)

  // prologue: ricci pairs for it = 0
  {
    const int j = ph * JPI + tid * JQ;
#pragma unroll
    for (int r = 0; r < MROWS; ++r)
      rv[0][r] = *(const v2f*)(rbase + (size_t)r * N_NODES + j);
  }

#pragma unroll
  for (int it = 0; it < ITERS; ++it) {
    const int cur = it & 1, nxt = cur ^ 1;
    const int j = ((it + ph) & (ITERS - 1)) * JPI + tid * JQ;

    // ---- pi rows j, j+1 FIRST (oldest in vmcnt order): one base, imm offs
    const float* pb = pi + (size_t)j * N_COMM;
    v4f p0[4], p1[4];
#pragma unroll
    for (int q = 0; q < 4; ++q) p0[q] = *(const v4f*)(pb + 4 * q);
#pragma unroll
    for (int q = 0; q < 4; ++q) p1[q] = *(const v4f*)(pb + N_COMM + 4 * q);

    // ---- next-iter ricci prefetch LAST among loads (newest) ----
    if (it + 1 < ITERS) {
      const int jn = ((it + 1 + ph) & (ITERS - 1)) * JPI + tid * JQ;
#pragma unroll
      for (int r = 0; r < MROWS; ++r)
        rv[nxt][r] = *(const v2f*)(rbase + (size_t)r * N_NODES + jn);
    }

    // ---- FMAs: consume pi (this iter) + rv (prefetched last iter) ----
#pragma unroll
    for (int r = 0; r < MROWS; ++r) {
      const float rx = rv[cur][r].x;
      const float ry = rv[cur][r].y;
#pragma unroll
      for (int q = 0; q < 4; ++q)
        acc[r][q] += rx * p0[q] + ry * p1[q];
    }
  }

  // per-thread epilogue: fold acc with pi rows i0..i0+3 (broadcast loads)
  float fintra = 0.f, finter = 0.f;
#pragma unroll
  for (int r = 0; r < MROWS; ++r) {
    const float* pr = pi + (size_t)(i0 + r) * N_COMM;
#pragma unroll
    for (int q = 0; q < 4; ++q) {
      v4f pv = *(const v4f*)(pr + 4 * q);
      v4f a  = acc[r][q];
      fintra += pv.x * a.x + pv.y * a.y + pv.z * a.z + pv.w * a.w;
      finter += a.x + a.y + a.z + a.w;
    }
  }

  // wave reduce (64 lanes) in double, then block reduce, 2 atomics/block
  double di = (double)fintra, dn = (double)finter;
#pragma unroll
  for (int off = 32; off > 0; off >>= 1) {
    di += __shfl_down(di, off);
    dn += __shfl_down(dn, off);
  }
  __shared__ double red[8];
  const int w = tid >> 6;
  if ((tid & 63) == 0) { red[w] = di; red[4 + w] = dn; }
  __syncthreads();
  if (tid == 0) {
    atomicAdd(&accum[0], red[0] + red[1] + red[2] + red[3]);
    atomicAdd(&accum[1], red[4] + red[5] + red[6] + red[7]);
    // last-block finalize (fused k_final): device-scope atomics + fences
    __threadfence();
    unsigned prev = atomicAdd(ctr, 1u);
    if (prev == (unsigned)gridDim.x - 1u) {
      __threadfence();
      double ia = atomicAdd(&accum[0], 0.0);   // coherent device-scope read
      double ir = atomicAdd(&accum[1], 0.0);
      const double KN  = (double)N_COMM * (double)N_NODES;
      const double KKN = (double)N_COMM * (double)N_COMM * (double)N_NODES;
      out[0] = (float)((double)alpha[0] * (ia / KN) - ir / KKN);
    }
  }
}

extern "C" void kernel_launch(void* const* d_in, const int* in_sizes, int n_in,
                              void* d_out, int out_size, void* d_ws, size_t ws_size,
                              hipStream_t stream) {
  (void)in_sizes; (void)n_in; (void)out_size; (void)ws_size;

  const float* node  = (const float*)d_in[0];  // (3, 8192, 64) fp32
  const float* comm  = (const float*)d_in[1];  // (16, 64) fp32
  const float* ricci = (const float*)d_in[2];  // (8192, 8192) fp32
  const float* alpha = (const float*)d_in[3];  // scalar fp32
  float* out = (float*)d_out;

  double*   accum = (double*)d_ws;                    // 2 doubles @ 0
  unsigned* ctr   = (unsigned*)((char*)d_ws + 16);    // finish counter
  float*    pi    = (float*)((char*)d_ws + 64);       // 512 KB

  // accum/ctr zeroed by k_pi thread 0 (in-stream, before k_main) -- no memset.
  hipLaunchKernelGGL(k_pi,   dim3((N_NODES * N_COMM) / 256), dim3(256), 0, stream,
                     node, comm, pi, accum, ctr);
  hipLaunchKernelGGL(k_main, dim3(N_NODES / MROWS), dim3(256), 0, stream,
                     ricci, pi, alpha, accum, ctr, out);
}

// Round 2
// 470.079 us; speedup vs baseline: 1.2836x; 1.2836x over previous
//
#include <hip/hip_runtime.h>
#include <math.h>

#define N_NODES 8192
#define N_COMM 16
#define DIMS 64
#define ROWS 32                      // ricci rows per block (i-chunk)
#define JS 1024                      // j-strip per block: 256 thr x 4
#define NJB (N_NODES / JS)           // 8 j-strips
#define NIB (N_NODES / ROWS)         // 256 i-chunks -> grid 2048
#define PITS (N_NODES + 64)          // piT row stride (padded: L2 channel spread)

typedef float v4f __attribute__((ext_vector_type(4)));

// ---------------------------------------------------------------------------
// Kernel 1: pi[i,k] = softmax_k( sqrt(d_euc^2 + d_lor^2 + d_sph^2) )
// One lane per (node, k): t = i*16 + k. 16-lane softmax via shfl_xor(1,2,4,8).
// Writes pi row-major (k_main scalar row loads) AND transposed padded piT
// (k_main coalesced column-fragment loads). Thread 0 zeroes accum + counter.
// ---------------------------------------------------------------------------
__global__ __launch_bounds__(256) void k_pi(
    const float* __restrict__ node,   // (3, 8192, 64)
    const float* __restrict__ comm,   // (16, 64)
    float* __restrict__ pi,           // (8192, 16)
    float* __restrict__ piT,          // (16, PITS)
    double* __restrict__ accum,       // [0]=intra, [1]=inter
    unsigned* __restrict__ ctr)       // k_main finish counter
{
  const int t = blockIdx.x * blockDim.x + threadIdx.x;  // 0..131071
  if (t == 0) { accum[0] = 0.0; accum[1] = 0.0; *ctr = 0u; }
  const int i = t >> 4;
  const int k = t & 15;

  const float* xe = node + (size_t)i * DIMS;                  // Euclidean (curv 0)
  const float* xl = xe + (size_t)N_NODES * DIMS;              // Lorentz  (curv -1)
  const float* xs = xl + (size_t)N_NODES * DIMS;              // Sphere   (curv +1)
  const float* c  = comm + k * DIMS;

  float de = 0.f, il = 0.f, isp = 0.f;
#pragma unroll
  for (int d = 0; d < DIMS; d += 4) {
    v4f a  = *(const v4f*)(xe + d);
    v4f b  = *(const v4f*)(xl + d);
    v4f e  = *(const v4f*)(xs + d);
    v4f cv = *(const v4f*)(c + d);
    v4f df = a - cv;
    de  += df.x * df.x + df.y * df.y + df.z * df.z + df.w * df.w;
    il  += b.x * cv.x + b.y * cv.y + b.z * cv.z + b.w * cv.w;
    isp += e.x * cv.x + e.y * cv.y + e.z * cv.z + e.w * cv.w;
  }

  // Lorentz (kk = 1): lip = <x,c> - 2*x0*c0 ; d = arccosh(max(-lip, 1+eps))
  float lip = il - 2.0f * xl[0] * c[0];
  float arg = fmaxf(-lip, 1.0f + 1e-7f);
  float d1  = acoshf(arg);
  // Sphere: d = arccos(clip(<x,c>, -1+eps, 1-eps))
  float cs = fminf(fmaxf(isp, -1.0f + 1e-7f), 1.0f - 1e-7f);
  float d2 = acosf(cs);

  float dn = sqrtf(de + d1 * d1 + d2 * d2);

  // softmax over the 16 lanes sharing this node (lane mask bits 0..3)
  float m = dn;
#pragma unroll
  for (int off = 1; off < 16; off <<= 1) m = fmaxf(m, __shfl_xor(m, off));
  float ex = expf(dn - m);
  float ss = ex;
#pragma unroll
  for (int off = 1; off < 16; off <<= 1) ss += __shfl_xor(ss, off);

  float v = ex / ss;
  pi[t] = v;                     // coalesced
  piT[k * PITS + i] = v;         // scattered, tiny (one store/thread)
}

// ---------------------------------------------------------------------------
// Kernel 2: 2-D tiling. Block = (32 ricci rows) x (j-strip of 1024).
// Thread owns ONE fixed j-quad for the whole block lifetime:
//   - p[k] = piT[k][jq] loaded ONCE per block (16 coalesced dwordx4).
//     (R1 lesson: row-major pi reads had 128B inter-lane stride -> 64 lines
//      per instr -> request-rate bound at 7% VALU. piT is lane-consecutive.)
//   - per row: 1 coalesced ricci dwordx4 + 64 FMA (s_k) + uniform pi[i][*]
//     fold (scalar s_load path, lgkmcnt -- decoupled from vmcnt stream).
//   - no per-row cross-thread reduction: fold s_k immediately into two
//     per-thread scalars (intra uses pi[i][k]; inter = plain ricci sum,
//     since softmax rows sum to 1 -- verified by R0/R1 absmax=0.0).
// Distance-2 row prefetch (rA/rB), issue order: prefetch newest, consume
// data loaded one unrolled iter earlier. ~100 VGPR -> ~5 waves/SIMD.
// Epilogue: last block finalizes (fused k_final).
// ---------------------------------------------------------------------------
__global__ __launch_bounds__(256) void k_main(
    const float* __restrict__ ricci,   // (8192, 8192)
    const float* __restrict__ pi,      // (8192, 16) row-major
    const float* __restrict__ piT,     // (16, PITS)
    const float* __restrict__ alpha,   // scalar
    double* __restrict__ accum,        // [0]=intra_sum, [1]=inter_sum
    unsigned* __restrict__ ctr,
    float* __restrict__ out)
{
  const int tid = threadIdx.x;
  const int jb  = blockIdx.x & (NJB - 1);   // j-strip
  const int ib  = blockIdx.x >> 3;          // i-chunk (log2(NJB)=3)
  const int i0  = ib * ROWS;
  const int j   = jb * JS + tid * 4;

  // one-time pi column fragments for this thread's j-quad (coalesced)
  v4f p[N_COMM];
#pragma unroll
  for (int k = 0; k < N_COMM; ++k)
    p[k] = *(const v4f*)(piT + (size_t)k * PITS + j);

  const float* rptr = ricci + (size_t)i0 * N_NODES + j;

  float fi[4] = {0.f, 0.f, 0.f, 0.f};   // split intra chains (latency)
  float finter = 0.f;

  // prologue: rows 0,1
  v4f rA = *(const v4f*)(rptr);
  v4f rB = *(const v4f*)(rptr + N_NODES);

#pragma unroll
  for (int ir = 0; ir < ROWS; ir += 2) {
    // uniform pi rows for this pair (scalar-load path, lgkmcnt)
    const float* prow0 = pi + (size_t)(i0 + ir) * N_COMM;
    const float* prow1 = prow0 + N_COMM;

    v4f r0 = rA, r1 = rB;
    // prefetch rows ir+2, ir+3 (newest in vmcnt order -> never waited here)
    if (ir + 2 < ROWS) {
      rA = *(const v4f*)(rptr + (size_t)(ir + 2) * N_NODES);
      rB = *(const v4f*)(rptr + (size_t)(ir + 3) * N_NODES);
    }

    // row ir
#pragma unroll
    for (int k = 0; k < N_COMM; ++k) {
      float sk = r0.x * p[k].x + r0.y * p[k].y + r0.z * p[k].z + r0.w * p[k].w;
      fi[k & 3] += prow0[k] * sk;
    }
    finter += (r0.x + r0.y) + (r0.z + r0.w);

    // row ir+1
#pragma unroll
    for (int k = 0; k < N_COMM; ++k) {
      float sk = r1.x * p[k].x + r1.y * p[k].y + r1.z * p[k].z + r1.w * p[k].w;
      fi[k & 3] += prow1[k] * sk;
    }
    finter += (r1.x + r1.y) + (r1.z + r1.w);
  }

  float fintra = (fi[0] + fi[1]) + (fi[2] + fi[3]);

  // wave reduce (64 lanes) in double, then block reduce, 2 atomics/block
  double di = (double)fintra, dn = (double)finter;
#pragma unroll
  for (int off = 32; off > 0; off >>= 1) {
    di += __shfl_down(di, off);
    dn += __shfl_down(dn, off);
  }
  __shared__ double red[8];
  const int w = tid >> 6;
  if ((tid & 63) == 0) { red[w] = di; red[4 + w] = dn; }
  __syncthreads();
  if (tid == 0) {
    atomicAdd(&accum[0], red[0] + red[1] + red[2] + red[3]);
    atomicAdd(&accum[1], red[4] + red[5] + red[6] + red[7]);
    // last-block finalize (fused k_final): device-scope atomics + fences
    __threadfence();
    unsigned prev = atomicAdd(ctr, 1u);
    if (prev == (unsigned)gridDim.x - 1u) {
      __threadfence();
      double ia = atomicAdd(&accum[0], 0.0);   // coherent device-scope read
      double ir = atomicAdd(&accum[1], 0.0);
      const double KN  = (double)N_COMM * (double)N_NODES;
      const double KKN = (double)N_COMM * (double)N_COMM * (double)N_NODES;
      out[0] = (float)((double)alpha[0] * (ia / KN) - ir / KKN);
    }
  }
}

extern "C" void kernel_launch(void* const* d_in, const int* in_sizes, int n_in,
                              void* d_out, int out_size, void* d_ws, size_t ws_size,
                              hipStream_t stream) {
  (void)in_sizes; (void)n_in; (void)out_size; (void)ws_size;

  const float* node  = (const float*)d_in[0];  // (3, 8192, 64) fp32
  const float* comm  = (const float*)d_in[1];  // (16, 64) fp32
  const float* ricci = (const float*)d_in[2];  // (8192, 8192) fp32
  const float* alpha = (const float*)d_in[3];  // scalar fp32
  float* out = (float*)d_out;

  double*   accum = (double*)d_ws;                         // 2 doubles @ 0
  unsigned* ctr   = (unsigned*)((char*)d_ws + 16);         // finish counter
  float*    pi    = (float*)((char*)d_ws + 64);            // 512 KB
  float*    piT   = (float*)((char*)d_ws + 64 + 524288);   // 16*PITS*4 = 528 KB

  // accum/ctr zeroed by k_pi thread 0 (in-stream, before k_main) -- no memset.
  hipLaunchKernelGGL(k_pi,   dim3((N_NODES * N_COMM) / 256), dim3(256), 0, stream,
                     node, comm, pi, piT, accum, ctr);
  hipLaunchKernelGGL(k_main, dim3(NIB * NJB), dim3(256), 0, stream,
                     ricci, pi, piT, alpha, accum, ctr, out);
}